// Round 13
// baseline (183.225 us; speedup 1.0000x reference)
//
#include <hip/hip_runtime.h>

#define NN 5000
#define EE 10000
#define F_IN 16
#define F_EDGE 4
#define H 96
#define EHD 16
#define HID3 32
#define T_CHEB 5
#define L_LAYERS 10
#define C_OUT 3
#define LN_EPSF 1e-5f
#define KW 576    // stacked K: 4 attr mats + const mat + root
#define MD 32     // ELL max in-degree (dataset max ~13)
#define BM2 16    // rows per layer block
#define NBT2 313  // ceil(5000/16)
#define KC_N 36   // K chunks of 16
#define FRAG_PER_LAYER (6 * KC_N * 64)   // half4 units per layer (nt,kc,lane)

typedef float float4v __attribute__((ext_vector_type(4)));
typedef _Float16 half2v __attribute__((ext_vector_type(2)));
typedef _Float16 half4v __attribute__((ext_vector_type(4)));
typedef _Float16 half8v __attribute__((ext_vector_type(8)));

// Proven on this hardware in R9/R10/R12 (absmax 1.56e-2):
#define MFMA16(a, b, c) __builtin_amdgcn_mfma_f32_16x16x16f16((a), (b), (c), 0, 0, 0)

// ========= front-end: M_stack (576x96) to f16 B-fragments + ELL setup =========
// Block 0: ELL + deg/cnt via LDS int atomics (no prior memset needed).
// Blocks 1..360: Mfrag.
// B-frag (16x16x16): lane = n15 + 16*g holds B[k = kc*16 + 4g + e][col = nt*16 + n15]
__global__ __launch_bounds__(256) void k_front(
        const float* __restrict__ enc_w, const float* __restrict__ enc_b,
        const float* __restrict__ w1, const float* __restrict__ b1,
        const float* __restrict__ w2, const float* __restrict__ b2,
        const float* __restrict__ root,
        const int* __restrict__ row, const int* __restrict__ col,
        const float* __restrict__ eattr,
        _Float16* __restrict__ Mf, float* __restrict__ deg,
        int* __restrict__ cnt, int* __restrict__ ell_r,
        float* __restrict__ ell_m, float4* __restrict__ ell_ea) {
    __shared__ int sdeg[NN];
    __shared__ int scnt[NN];
    if (blockIdx.x == 0) {
        for (int i = threadIdx.x; i < NN; i += 256) { sdeg[i] = 0; scnt[i] = 0; }
        __syncthreads();
        for (int e = threadIdx.x; e < EE; e += 256) {
            int r = row[e], c = col[e];
            float4 ea = *(const float4*)(eattr + e * F_EDGE);
            float m = (ea.x == 0.f && r != c) ? 1.f : 0.f;
            if (m != 0.f) atomicAdd(&sdeg[r], 1);
            int slot = atomicAdd(&scnt[c], 1);
            int p = c * MD + slot;
            ell_r[p] = r;
            ell_m[p] = m;
            ell_ea[p] = ea;
        }
        __syncthreads();
        for (int i = threadIdx.x; i < NN; i += 256) {
            deg[i] = (float)sdeg[i];
            cnt[i] = scnt[i];
        }
        return;
    }
    const int tid = (blockIdx.x - 1) * 256 + threadIdx.x;
    const int NTH = (gridDim.x - 1) * 256;
    for (int idx = tid; idx < L_LAYERS * H * H; idx += NTH) {
        int i = idx / (H * H);
        int m = idx % (H * H);      // m = h*96 + o   (h: inner K row, o: output col)
        int h = m / H, o = m % H;
        const float* w2i = w2 + (size_t)i * HID3 * H * H;
        const float* w1i = w1 + i * EHD * HID3;
        float hcol[HID3];
        #pragma unroll
        for (int k2 = 0; k2 < HID3; ++k2) hcol[k2] = w2i[(size_t)k2 * H * H + m];
        float tcol[EHD];
        #pragma unroll
        for (int ke = 0; ke < EHD; ++ke) {
            float s = 0.f;
            #pragma unroll
            for (int k2 = 0; k2 < HID3; ++k2) s += w1i[ke * HID3 + k2] * hcol[k2];
            tcol[ke] = s;
        }
        float vals[6];
        #pragma unroll
        for (int f = 0; f < F_EDGE; ++f) {
            float s = 0.f;
            #pragma unroll
            for (int ke = 0; ke < EHD; ++ke) s += enc_w[f * EHD + ke] * tcol[ke];
            vals[f] = s;
        }
        float c = b2[(size_t)i * H * H + m];
        #pragma unroll
        for (int ke = 0; ke < EHD; ++ke) c += enc_b[ke] * tcol[ke];
        #pragma unroll
        for (int k2 = 0; k2 < HID3; ++k2) c += b1[i * HID3 + k2] * hcol[k2];
        vals[4] = c;
        vals[5] = root[(size_t)i * H * H + m];
        int nt = o >> 4, n15 = o & 15;
        #pragma unroll
        for (int f = 0; f < 6; ++f) {
            int K = f * 96 + h;                      // stacked K index
            int kc = K >> 4, g2 = (K & 15) >> 2, e2 = K & 3;
            int lane = n15 + 16 * g2;
            Mf[((((size_t)i * 6 + nt) * KC_N + kc) * 64 + lane) * 4 + e2] = (_Float16)vals[f];
        }
    }
}

// ====== Cheb A: T1 and T2 in one pass (neighbor T1 recomputed on the fly) ======
__global__ void k_chebA(const int* __restrict__ cnt, const int* __restrict__ ell_r,
                        const float* __restrict__ ell_m, const float* __restrict__ deg,
                        const float* __restrict__ x,
                        float* __restrict__ T1, float* __restrict__ T2) {
    int t = blockIdx.x * blockDim.x + threadIdx.x;
    if (t >= NN * 4) return;
    int c = t >> 2, q = t & 3;
    float dc = deg[c];
    float dinvC = dc > 0.f ? rsqrtf(dc) : 0.f;
    int nc = cnt[c];
    const int* rp = ell_r + c * MD;
    const float* mp = ell_m + c * MD;
    float4 acc1 = make_float4(0.f, 0.f, 0.f, 0.f);
    float4 acc2 = make_float4(0.f, 0.f, 0.f, 0.f);
    for (int p = 0; p < nc; ++p) {
        if (mp[p] == 0.f) continue;
        int r = rp[p];
        float dinvR = rsqrtf(deg[r]);
        float4 xr = *(const float4*)(x + (size_t)r * F_IN + q * 4);
        acc1.x = fmaf(dinvR, xr.x, acc1.x); acc1.y = fmaf(dinvR, xr.y, acc1.y);
        acc1.z = fmaf(dinvR, xr.z, acc1.z); acc1.w = fmaf(dinvR, xr.w, acc1.w);
        float4 a = make_float4(0.f, 0.f, 0.f, 0.f);
        int nr = cnt[r];
        const int* rp2 = ell_r + r * MD;
        const float* mp2 = ell_m + r * MD;
        for (int p2 = 0; p2 < nr; ++p2) {
            if (mp2[p2] == 0.f) continue;
            int r2 = rp2[p2];
            float w2v = rsqrtf(deg[r2]);
            float4 x2 = *(const float4*)(x + (size_t)r2 * F_IN + q * 4);
            a.x = fmaf(w2v, x2.x, a.x); a.y = fmaf(w2v, x2.y, a.y);
            a.z = fmaf(w2v, x2.z, a.z); a.w = fmaf(w2v, x2.w, a.w);
        }
        float f1 = -dinvR;
        acc2.x = fmaf(dinvR, f1 * a.x, acc2.x); acc2.y = fmaf(dinvR, f1 * a.y, acc2.y);
        acc2.z = fmaf(dinvR, f1 * a.z, acc2.z); acc2.w = fmaf(dinvR, f1 * a.w, acc2.w);
    }
    float4 xc = *(const float4*)(x + (size_t)c * F_IN + q * 4);
    float f = -dinvC;
    *(float4*)(T1 + (size_t)c * F_IN + q * 4) =
        make_float4(f * acc1.x, f * acc1.y, f * acc1.z, f * acc1.w);
    float f2 = -2.f * dinvC;
    *(float4*)(T2 + (size_t)c * F_IN + q * 4) =
        make_float4(f2 * acc2.x - xc.x, f2 * acc2.y - xc.y,
                    f2 * acc2.z - xc.z, f2 * acc2.w - xc.w);
}

// ====== Cheb B: T3 (own, LDS), T4 (own, neighbor-T3 on the fly), cheb_out -> v0 f16 ======
__global__ __launch_bounds__(256) void k_chebB(
        const int* __restrict__ cnt, const int* __restrict__ ell_r,
        const float* __restrict__ ell_m, const float* __restrict__ deg,
        const float* __restrict__ x, const float* __restrict__ T1,
        const float* __restrict__ T2, const float* __restrict__ cheb_w,
        const float* __restrict__ cheb_b, _Float16* __restrict__ vout) {
    __shared__ float wlds[T_CHEB * F_IN][H];   // 30 KB
    __shared__ float t34[2][64][F_IN];         // 8 KB
    const int n0 = blockIdx.x * 64;
    const int t = threadIdx.x;
    for (int i = t; i < T_CHEB * F_IN * H / 4; i += 256)
        ((float4*)wlds)[i] = ((const float4*)cheb_w)[i];
    {
        int c = n0 + (t >> 2), q = t & 3;
        if (c < NN) {
            float dc = deg[c];
            float dinvC = dc > 0.f ? rsqrtf(dc) : 0.f;
            int nc = cnt[c];
            const int* rp = ell_r + c * MD;
            const float* mp = ell_m + c * MD;
            float4 a3 = make_float4(0.f, 0.f, 0.f, 0.f);
            float4 a4 = make_float4(0.f, 0.f, 0.f, 0.f);
            for (int p = 0; p < nc; ++p) {
                if (mp[p] == 0.f) continue;
                int r = rp[p];
                float dinvR = rsqrtf(deg[r]);
                float4 t2r = *(const float4*)(T2 + (size_t)r * F_IN + q * 4);
                a3.x = fmaf(dinvR, t2r.x, a3.x); a3.y = fmaf(dinvR, t2r.y, a3.y);
                a3.z = fmaf(dinvR, t2r.z, a3.z); a3.w = fmaf(dinvR, t2r.w, a3.w);
                float4 b = make_float4(0.f, 0.f, 0.f, 0.f);
                int nr = cnt[r];
                const int* rp2 = ell_r + r * MD;
                const float* mp2 = ell_m + r * MD;
                for (int p2 = 0; p2 < nr; ++p2) {
                    if (mp2[p2] == 0.f) continue;
                    int r2 = rp2[p2];
                    float w2v = rsqrtf(deg[r2]);
                    float4 t2b = *(const float4*)(T2 + (size_t)r2 * F_IN + q * 4);
                    b.x = fmaf(w2v, t2b.x, b.x); b.y = fmaf(w2v, t2b.y, b.y);
                    b.z = fmaf(w2v, t2b.z, b.z); b.w = fmaf(w2v, t2b.w, b.w);
                }
                float fr = -2.f * dinvR;
                float4 t1r = *(const float4*)(T1 + (size_t)r * F_IN + q * 4);
                float4 t3r = make_float4(fr * b.x - t1r.x, fr * b.y - t1r.y,
                                         fr * b.z - t1r.z, fr * b.w - t1r.w);
                a4.x = fmaf(dinvR, t3r.x, a4.x); a4.y = fmaf(dinvR, t3r.y, a4.y);
                a4.z = fmaf(dinvR, t3r.z, a4.z); a4.w = fmaf(dinvR, t3r.w, a4.w);
            }
            float f3 = -2.f * dinvC;
            float4 t1c = *(const float4*)(T1 + (size_t)c * F_IN + q * 4);
            float4 t2c = *(const float4*)(T2 + (size_t)c * F_IN + q * 4);
            int lr = t >> 2;
            *(float4*)&t34[0][lr][q * 4] =
                make_float4(f3 * a3.x - t1c.x, f3 * a3.y - t1c.y,
                            f3 * a3.z - t1c.z, f3 * a3.w - t1c.w);
            *(float4*)&t34[1][lr][q * 4] =
                make_float4(f3 * a4.x - t2c.x, f3 * a4.y - t2c.y,
                            f3 * a4.z - t2c.z, f3 * a4.w - t2c.w);
        }
    }
    __syncthreads();
    {
        int lr = t >> 2, n = n0 + lr, cseg = t & 3;
        if (n >= NN) return;
        float txv[T_CHEB * F_IN];
        #pragma unroll
        for (int q = 0; q < 4; ++q) {
            *(float4*)(txv + q * 4)      = *(const float4*)(x  + (size_t)n * F_IN + q * 4);
            *(float4*)(txv + 16 + q * 4) = *(const float4*)(T1 + (size_t)n * F_IN + q * 4);
            *(float4*)(txv + 32 + q * 4) = *(const float4*)(T2 + (size_t)n * F_IN + q * 4);
            *(float4*)(txv + 48 + q * 4) = *(const float4*)&t34[0][lr][q * 4];
            *(float4*)(txv + 64 + q * 4) = *(const float4*)&t34[1][lr][q * 4];
        }
        _Float16* vr = vout + (size_t)n * H + cseg * 24;
        #pragma unroll 4
        for (int c = 0; c < 24; ++c) {
            int o = cseg * 24 + c;
            float s = cheb_b[o];
            #pragma unroll
            for (int kf = 0; kf < T_CHEB * F_IN; ++kf)
                s = fmaf(txv[kf], wlds[kf][o], s);
            vr[c] = (_Float16)s;
        }
    }
}

// ====== per-layer: z-aggregate + 4-way split-K MFMA (16x96, K=576) + LN epilogue ======
// grid 313 x 512 (8 waves). wave: nt-half = wid&1, K-quarter = wid>>1 (9 kc of 16).
// B fragments are register-prefetched BEFORE phase 1 so their L2 latency hides
// under the gather; __syncthreads' vmcnt drain guarantees arrival.
__global__ __launch_bounds__(512) void k_layer(
        const _Float16* __restrict__ vcur, const float* __restrict__ hres,
        const int* __restrict__ cnt, const int* __restrict__ ell_r,
        const float4* __restrict__ ell_ea, const _Float16* __restrict__ MfL,
        const float* __restrict__ cb, const float* __restrict__ lg,
        const float* __restrict__ lb, const float* __restrict__ lin_w,
        const float* __restrict__ lin_b,
        float* __restrict__ hnext, _Float16* __restrict__ vnext,
        float* __restrict__ outp, int isLast) {
    __shared__ __align__(16) _Float16 zs[BM2][584];   // 18.7 KB
    __shared__ float hop[4][BM2][100];                // 25.6 KB
    const int n0 = blockIdx.x * BM2;
    const int t = threadIdx.x;

    // ---- phase 0: register-prefetch this wave's B fragments (27 x half4) ----
    const int wid = t >> 6, l = t & 63;
    const int n15 = l & 15, g = l >> 4;
    const int ntBase = (wid & 1) * 3;
    const int kSeg = wid >> 1;            // 0..3
    const int kcBase = kSeg * 9;
    const half4v* Mf4 = (const half4v*)MfL;
    half4v bfr[3][9];
    #pragma unroll
    for (int j = 0; j < 3; ++j) {
        const half4v* Bp = Mf4 + ((size_t)(ntBase + j) * KC_N + kcBase) * 64 + l;
        #pragma unroll
        for (int kk = 0; kk < 9; ++kk) bfr[j][kk] = Bp[kk * 64];
    }

    // ---- phase 1: build z rows (16 lanes/row, first 256 threads) ----
    if (t < 256) {
        int r = t >> 4, lane16 = t & 15;
        int gn = n0 + r, c0 = lane16 * 6;
        float accf[5][6] = {};
        half2v self0 = (half2v)(_Float16)0.f, self1 = self0, self2 = self0;
        if (gn < NN) {
            const _Float16* sv = vcur + (size_t)gn * H + c0;
            self0 = *(const half2v*)(sv + 0);
            self1 = *(const half2v*)(sv + 2);
            self2 = *(const half2v*)(sv + 4);
            int nc = cnt[gn];
            const int* rp = ell_r + gn * MD;
            const float4* eap = ell_ea + gn * MD;
            for (int p = 0; p < nc; ++p) {
                int r2 = rp[p];
                float4 ea = eap[p];
                const _Float16* vv = vcur + (size_t)r2 * H + c0;
                half2v v0 = *(const half2v*)(vv + 0);
                half2v v1 = *(const half2v*)(vv + 2);
                half2v v2 = *(const half2v*)(vv + 4);
                float vf[6] = {(float)v0[0], (float)v0[1], (float)v1[0],
                               (float)v1[1], (float)v2[0], (float)v2[1]};
                const float cf[4] = {ea.x, ea.y, ea.z, ea.w};
                #pragma unroll
                for (int f = 0; f < 4; ++f)
                    #pragma unroll
                    for (int j = 0; j < 6; ++j)
                        accf[f][j] = fmaf(cf[f], vf[j], accf[f][j]);
                #pragma unroll
                for (int j = 0; j < 6; ++j) accf[4][j] += vf[j];
            }
        }
        #pragma unroll
        for (int f = 0; f < 5; ++f) {
            _Float16* zp = &zs[r][f * 96 + c0];
            *(half2v*)(zp + 0) = half2v{(_Float16)accf[f][0], (_Float16)accf[f][1]};
            *(half2v*)(zp + 2) = half2v{(_Float16)accf[f][2], (_Float16)accf[f][3]};
            *(half2v*)(zp + 4) = half2v{(_Float16)accf[f][4], (_Float16)accf[f][5]};
        }
        _Float16* zp = &zs[r][480 + c0];
        *(half2v*)(zp + 0) = self0;
        *(half2v*)(zp + 2) = self1;
        *(half2v*)(zp + 4) = self2;
    }
    __syncthreads();

    // ---- phase 2: MFMA with prefetched B ----
    {
        half4v af[9];
        #pragma unroll
        for (int kk = 0; kk < 9; ++kk)
            af[kk] = *(const half4v*)&zs[n15][(kcBase + kk) * 16 + 4 * g];
        float4v acc3[3] = {};
        #pragma unroll
        for (int j = 0; j < 3; ++j)
            #pragma unroll
            for (int kk = 0; kk < 9; ++kk)
                acc3[j] = MFMA16(af[kk], bfr[j][kk], acc3[j]);
        #pragma unroll
        for (int j = 0; j < 3; ++j) {
            int cc = (ntBase + j) * 16 + n15;
            #pragma unroll
            for (int e = 0; e < 4; ++e)
                hop[kSeg][4 * g + e][cc] = acc3[j][e];
        }
    }
    __syncthreads();

    // ---- phase 3: combine partials + residual + LN + ReLU (or linear head) ----
    if (t < 256) {
        int r = t >> 4, lane16 = t & 15;
        int gn = n0 + r, c0 = lane16 * 6;
        float hv[6];
        #pragma unroll
        for (int j = 0; j < 6; ++j)
            hv[j] = hop[0][r][c0 + j] + hop[1][r][c0 + j]
                  + hop[2][r][c0 + j] + hop[3][r][c0 + j] + cb[c0 + j];
        if (hres && gn < NN) {
            const float* rp = hres + (size_t)gn * H + c0;
            #pragma unroll
            for (int j = 0; j < 6; j += 2) {
                float2 rv = *(const float2*)(rp + j);
                hv[j] += rv.x; hv[j + 1] += rv.y;
            }
        }
        if (!isLast && gn < NN) {
            float* hp = hnext + (size_t)gn * H + c0;
            #pragma unroll
            for (int j = 0; j < 6; j += 2)
                *(float2*)(hp + j) = make_float2(hv[j], hv[j + 1]);
        }
        float s = 0.f;
        #pragma unroll
        for (int j = 0; j < 6; ++j) s += hv[j];
        s += __shfl_xor(s, 1); s += __shfl_xor(s, 2);
        s += __shfl_xor(s, 4); s += __shfl_xor(s, 8);
        float mu = s * (1.0f / H);
        float vvr = 0.f;
        #pragma unroll
        for (int j = 0; j < 6; ++j) { float d = hv[j] - mu; vvr += d * d; }
        vvr += __shfl_xor(vvr, 1); vvr += __shfl_xor(vvr, 2);
        vvr += __shfl_xor(vvr, 4); vvr += __shfl_xor(vvr, 8);
        float is = rsqrtf(vvr * (1.0f / H) + LN_EPSF);
        const float* gp = lg + c0;
        const float* bp = lb + c0;
        float yv[6];
        #pragma unroll
        for (int j = 0; j < 6; ++j)
            yv[j] = fmaxf(fmaf((hv[j] - mu) * is, gp[j], bp[j]), 0.f);
        if (!isLast) {
            if (gn < NN) {
                _Float16* vp = vnext + (size_t)gn * H + c0;
                *(half2v*)(vp + 0) = half2v{(_Float16)yv[0], (_Float16)yv[1]};
                *(half2v*)(vp + 2) = half2v{(_Float16)yv[2], (_Float16)yv[3]};
                *(half2v*)(vp + 4) = half2v{(_Float16)yv[4], (_Float16)yv[5]};
            }
        } else {
            float a0 = 0.f, a1 = 0.f, a2 = 0.f;
            #pragma unroll
            for (int j = 0; j < 6; ++j) {
                int oo = c0 + j;
                a0 = fmaf(yv[j], lin_w[oo * C_OUT + 0], a0);
                a1 = fmaf(yv[j], lin_w[oo * C_OUT + 1], a1);
                a2 = fmaf(yv[j], lin_w[oo * C_OUT + 2], a2);
            }
            a0 += __shfl_xor(a0, 1); a0 += __shfl_xor(a0, 2);
            a0 += __shfl_xor(a0, 4); a0 += __shfl_xor(a0, 8);
            a1 += __shfl_xor(a1, 1); a1 += __shfl_xor(a1, 2);
            a1 += __shfl_xor(a1, 4); a1 += __shfl_xor(a1, 8);
            a2 += __shfl_xor(a2, 1); a2 += __shfl_xor(a2, 2);
            a2 += __shfl_xor(a2, 4); a2 += __shfl_xor(a2, 8);
            if (lane16 == 0 && gn < NN) {
                outp[gn * C_OUT + 0] = a0 + lin_b[0];
                outp[gn * C_OUT + 1] = a1 + lin_b[1];
                outp[gn * C_OUT + 2] = a2 + lin_b[2];
            }
        }
    }
}

extern "C" void kernel_launch(void* const* d_in, const int* in_sizes, int n_in,
                              void* d_out, int out_size, void* d_ws, size_t ws_size,
                              hipStream_t stream) {
    const float* x      = (const float*)d_in[0];
    const int*   row    = (const int*)d_in[1];
    const int*   col    = (const int*)d_in[1] + EE;
    const float* eattr  = (const float*)d_in[2];
    const float* cheb_w = (const float*)d_in[3];
    const float* cheb_b = (const float*)d_in[4];
    const float* enc_w  = (const float*)d_in[5];
    const float* enc_b  = (const float*)d_in[6];
    const float* w1     = (const float*)d_in[7];
    const float* b1     = (const float*)d_in[8];
    const float* w2     = (const float*)d_in[9];
    const float* b2     = (const float*)d_in[10];
    const float* root   = (const float*)d_in[11];
    const float* conv_b = (const float*)d_in[12];
    const float* ln_g   = (const float*)d_in[13];
    const float* ln_b   = (const float*)d_in[14];
    const float* lin_w  = (const float*)d_in[15];
    const float* lin_b  = (const float*)d_in[16];

    char* base = (char*)d_ws;
    size_t off = 0;
    auto alloc = [&](size_t nbytes) {
        char* p = base + off;
        off += (nbytes + 255) / 256 * 256;
        return p;
    };
    float*    deg    = (float*)alloc(NN * 4);
    int*      cnt    = (int*)  alloc(NN * 4);
    _Float16* Mfrag  = (_Float16*)alloc((size_t)L_LAYERS * FRAG_PER_LAYER * 4 * 2);
    float*    T1     = (float*)alloc((size_t)NN * F_IN * 4);
    float*    T2     = (float*)alloc((size_t)NN * F_IN * 4);
    int*      ell_r  = (int*)  alloc((size_t)NN * MD * 4);
    float*    ell_m  = (float*)alloc((size_t)NN * MD * 4);
    float4*   ell_ea = (float4*)alloc((size_t)NN * MD * 16);
    _Float16* v0     = (_Float16*)alloc((size_t)NN * H * 2);
    _Float16* v1     = (_Float16*)alloc((size_t)NN * H * 2);
    float*    hA     = (float*)alloc((size_t)NN * H * 4);
    float*    hB     = (float*)alloc((size_t)NN * H * 4);
    (void)ws_size; (void)n_in; (void)in_sizes; (void)out_size;

    const int B = 256;
    auto G = [](long n, int b) { return (int)((n + b - 1) / b); };

    k_front<<<361, B, 0, stream>>>(enc_w, enc_b, w1, b1, w2, b2, root,
                                   row, col, eattr, Mfrag, deg, cnt, ell_r, ell_m, ell_ea);
    k_chebA<<<G((long)NN * 4, B), B, 0, stream>>>(cnt, ell_r, ell_m, deg, x, T1, T2);
    k_chebB<<<G(NN, 64), B, 0, stream>>>(cnt, ell_r, ell_m, deg, x, T1, T2,
                                         cheb_w, cheb_b, v0);

    _Float16* vbuf[2] = { v0, v1 };
    float*    hbuf[2] = { hA, hB };
    for (int li = 0; li < L_LAYERS; ++li) {
        int isLast = (li == L_LAYERS - 1);
        const _Float16* vcur = vbuf[li & 1];
        _Float16*       vnx  = vbuf[(li + 1) & 1];
        const float*    hres = (li > 0) ? hbuf[(li + 1) & 1] : nullptr;
        float*          hnx  = hbuf[li & 1];
        const float* elg = isLast ? ln_g : ln_g + (li + 1) * H;
        const float* elb = isLast ? ln_b : ln_b + (li + 1) * H;
        k_layer<<<NBT2, 512, 0, stream>>>(
            vcur, hres, cnt, ell_r, ell_ea,
            Mfrag + (size_t)li * FRAG_PER_LAYER * 4,
            conv_b + li * H, elg, elb, lin_w, lin_b,
            hnx, vnx, (float*)d_out, isLast);
    }
}

// Round 14
// 163.543 us; speedup vs baseline: 1.1204x; 1.1204x over previous
//
#include <hip/hip_runtime.h>

#define NN 5000
#define EE 10000
#define F_IN 16
#define F_EDGE 4
#define H 96
#define EHD 16
#define HID3 32
#define T_CHEB 5
#define L_LAYERS 10
#define C_OUT 3
#define LN_EPSF 1e-5f
#define KW 576    // stacked K: 4 attr mats + const mat + root
#define MD 32     // ELL max in-degree (dataset max ~13)
#define BM2 16    // rows per layer block
#define NBT2 313  // ceil(5000/16)
#define KC_N 36   // K chunks of 16
#define FRAG_PER_LAYER (6 * KC_N * 64)   // half4 units per layer (nt,kc,lane)

typedef float float4v __attribute__((ext_vector_type(4)));
typedef _Float16 half2v __attribute__((ext_vector_type(2)));
typedef _Float16 half4v __attribute__((ext_vector_type(4)));
typedef _Float16 half8v __attribute__((ext_vector_type(8)));

// Proven on this hardware in R9/R10/R12 (absmax 1.56e-2):
#define MFMA16(a, b, c) __builtin_amdgcn_mfma_f32_16x16x16f16((a), (b), (c), 0, 0, 0)

// ========= front-end: M_stack (576x96) to f16 B-fragments + ELL setup =========
// (R12 form: grid-strided, NO LDS — the R13 LDS-deg variant capped occupancy at 3.5%)
__global__ void k_front(const float* __restrict__ enc_w, const float* __restrict__ enc_b,
                        const float* __restrict__ w1, const float* __restrict__ b1,
                        const float* __restrict__ w2, const float* __restrict__ b2,
                        const float* __restrict__ root,
                        const int* __restrict__ row, const int* __restrict__ col,
                        const float* __restrict__ eattr,
                        _Float16* __restrict__ Mf, float* __restrict__ deg,
                        int* __restrict__ cnt, int* __restrict__ ell_r,
                        float* __restrict__ ell_m, float4* __restrict__ ell_ea) {
    const int tid = blockIdx.x * blockDim.x + threadIdx.x;
    const int NTH = gridDim.x * blockDim.x;
    for (int idx = tid; idx < L_LAYERS * H * H; idx += NTH) {
        int i = idx / (H * H);
        int m = idx % (H * H);      // m = h*96 + o   (h: inner K row, o: output col)
        int h = m / H, o = m % H;
        const float* w2i = w2 + (size_t)i * HID3 * H * H;
        const float* w1i = w1 + i * EHD * HID3;
        float hcol[HID3];
        #pragma unroll
        for (int k2 = 0; k2 < HID3; ++k2) hcol[k2] = w2i[(size_t)k2 * H * H + m];
        float tcol[EHD];
        #pragma unroll
        for (int ke = 0; ke < EHD; ++ke) {
            float s = 0.f;
            #pragma unroll
            for (int k2 = 0; k2 < HID3; ++k2) s += w1i[ke * HID3 + k2] * hcol[k2];
            tcol[ke] = s;
        }
        float vals[6];
        #pragma unroll
        for (int f = 0; f < F_EDGE; ++f) {
            float s = 0.f;
            #pragma unroll
            for (int ke = 0; ke < EHD; ++ke) s += enc_w[f * EHD + ke] * tcol[ke];
            vals[f] = s;
        }
        float c = b2[(size_t)i * H * H + m];
        #pragma unroll
        for (int ke = 0; ke < EHD; ++ke) c += enc_b[ke] * tcol[ke];
        #pragma unroll
        for (int k2 = 0; k2 < HID3; ++k2) c += b1[i * HID3 + k2] * hcol[k2];
        vals[4] = c;
        vals[5] = root[(size_t)i * H * H + m];
        int nt = o >> 4, n15 = o & 15;
        #pragma unroll
        for (int f = 0; f < 6; ++f) {
            int K = f * 96 + h;                      // stacked K index
            int kc = K >> 4, g2 = (K & 15) >> 2, e2 = K & 3;
            int lane = n15 + 16 * g2;
            Mf[((((size_t)i * 6 + nt) * KC_N + kc) * 64 + lane) * 4 + e2] = (_Float16)vals[f];
        }
    }
    for (int e = tid; e < EE; e += NTH) {
        int r = row[e], c = col[e];
        float4 ea = *(const float4*)(eattr + e * F_EDGE);
        float m = (ea.x == 0.f && r != c) ? 1.f : 0.f;
        if (m != 0.f) atomicAdd(&deg[r], 1.f);   // integer-valued: exact
        int slot = atomicAdd(&cnt[c], 1);
        int p = c * MD + slot;
        ell_r[p] = r;
        ell_m[p] = m;
        ell_ea[p] = ea;
    }
}

// ====== Cheb A: T1 and T2 in one pass (neighbor T1 recomputed on the fly) ======
__global__ void k_chebA(const int* __restrict__ cnt, const int* __restrict__ ell_r,
                        const float* __restrict__ ell_m, const float* __restrict__ deg,
                        const float* __restrict__ x,
                        float* __restrict__ T1, float* __restrict__ T2) {
    int t = blockIdx.x * blockDim.x + threadIdx.x;
    if (t >= NN * 4) return;
    int c = t >> 2, q = t & 3;
    float dc = deg[c];
    float dinvC = dc > 0.f ? rsqrtf(dc) : 0.f;
    int nc = cnt[c];
    const int* rp = ell_r + c * MD;
    const float* mp = ell_m + c * MD;
    float4 acc1 = make_float4(0.f, 0.f, 0.f, 0.f);
    float4 acc2 = make_float4(0.f, 0.f, 0.f, 0.f);
    for (int p = 0; p < nc; ++p) {
        if (mp[p] == 0.f) continue;
        int r = rp[p];
        float dinvR = rsqrtf(deg[r]);
        float4 xr = *(const float4*)(x + (size_t)r * F_IN + q * 4);
        acc1.x = fmaf(dinvR, xr.x, acc1.x); acc1.y = fmaf(dinvR, xr.y, acc1.y);
        acc1.z = fmaf(dinvR, xr.z, acc1.z); acc1.w = fmaf(dinvR, xr.w, acc1.w);
        float4 a = make_float4(0.f, 0.f, 0.f, 0.f);
        int nr = cnt[r];
        const int* rp2 = ell_r + r * MD;
        const float* mp2 = ell_m + r * MD;
        for (int p2 = 0; p2 < nr; ++p2) {
            if (mp2[p2] == 0.f) continue;
            int r2 = rp2[p2];
            float w2v = rsqrtf(deg[r2]);
            float4 x2 = *(const float4*)(x + (size_t)r2 * F_IN + q * 4);
            a.x = fmaf(w2v, x2.x, a.x); a.y = fmaf(w2v, x2.y, a.y);
            a.z = fmaf(w2v, x2.z, a.z); a.w = fmaf(w2v, x2.w, a.w);
        }
        float f1 = -dinvR;
        acc2.x = fmaf(dinvR, f1 * a.x, acc2.x); acc2.y = fmaf(dinvR, f1 * a.y, acc2.y);
        acc2.z = fmaf(dinvR, f1 * a.z, acc2.z); acc2.w = fmaf(dinvR, f1 * a.w, acc2.w);
    }
    float4 xc = *(const float4*)(x + (size_t)c * F_IN + q * 4);
    float f = -dinvC;
    *(float4*)(T1 + (size_t)c * F_IN + q * 4) =
        make_float4(f * acc1.x, f * acc1.y, f * acc1.z, f * acc1.w);
    float f2 = -2.f * dinvC;
    *(float4*)(T2 + (size_t)c * F_IN + q * 4) =
        make_float4(f2 * acc2.x - xc.x, f2 * acc2.y - xc.y,
                    f2 * acc2.z - xc.z, f2 * acc2.w - xc.w);
}

// ====== Cheb B: T3 (own, LDS), T4 (own, neighbor-T3 on the fly), cheb_out -> v0 f16 ======
__global__ __launch_bounds__(256) void k_chebB(
        const int* __restrict__ cnt, const int* __restrict__ ell_r,
        const float* __restrict__ ell_m, const float* __restrict__ deg,
        const float* __restrict__ x, const float* __restrict__ T1,
        const float* __restrict__ T2, const float* __restrict__ cheb_w,
        const float* __restrict__ cheb_b, _Float16* __restrict__ vout) {
    __shared__ float wlds[T_CHEB * F_IN][H];   // 30 KB
    __shared__ float t34[2][64][F_IN];         // 8 KB
    const int n0 = blockIdx.x * 64;
    const int t = threadIdx.x;
    for (int i = t; i < T_CHEB * F_IN * H / 4; i += 256)
        ((float4*)wlds)[i] = ((const float4*)cheb_w)[i];
    {
        int c = n0 + (t >> 2), q = t & 3;
        if (c < NN) {
            float dc = deg[c];
            float dinvC = dc > 0.f ? rsqrtf(dc) : 0.f;
            int nc = cnt[c];
            const int* rp = ell_r + c * MD;
            const float* mp = ell_m + c * MD;
            float4 a3 = make_float4(0.f, 0.f, 0.f, 0.f);
            float4 a4 = make_float4(0.f, 0.f, 0.f, 0.f);
            for (int p = 0; p < nc; ++p) {
                if (mp[p] == 0.f) continue;
                int r = rp[p];
                float dinvR = rsqrtf(deg[r]);
                float4 t2r = *(const float4*)(T2 + (size_t)r * F_IN + q * 4);
                a3.x = fmaf(dinvR, t2r.x, a3.x); a3.y = fmaf(dinvR, t2r.y, a3.y);
                a3.z = fmaf(dinvR, t2r.z, a3.z); a3.w = fmaf(dinvR, t2r.w, a3.w);
                float4 b = make_float4(0.f, 0.f, 0.f, 0.f);
                int nr = cnt[r];
                const int* rp2 = ell_r + r * MD;
                const float* mp2 = ell_m + r * MD;
                for (int p2 = 0; p2 < nr; ++p2) {
                    if (mp2[p2] == 0.f) continue;
                    int r2 = rp2[p2];
                    float w2v = rsqrtf(deg[r2]);
                    float4 t2b = *(const float4*)(T2 + (size_t)r2 * F_IN + q * 4);
                    b.x = fmaf(w2v, t2b.x, b.x); b.y = fmaf(w2v, t2b.y, b.y);
                    b.z = fmaf(w2v, t2b.z, b.z); b.w = fmaf(w2v, t2b.w, b.w);
                }
                float fr = -2.f * dinvR;
                float4 t1r = *(const float4*)(T1 + (size_t)r * F_IN + q * 4);
                float4 t3r = make_float4(fr * b.x - t1r.x, fr * b.y - t1r.y,
                                         fr * b.z - t1r.z, fr * b.w - t1r.w);
                a4.x = fmaf(dinvR, t3r.x, a4.x); a4.y = fmaf(dinvR, t3r.y, a4.y);
                a4.z = fmaf(dinvR, t3r.z, a4.z); a4.w = fmaf(dinvR, t3r.w, a4.w);
            }
            float f3 = -2.f * dinvC;
            float4 t1c = *(const float4*)(T1 + (size_t)c * F_IN + q * 4);
            float4 t2c = *(const float4*)(T2 + (size_t)c * F_IN + q * 4);
            int lr = t >> 2;
            *(float4*)&t34[0][lr][q * 4] =
                make_float4(f3 * a3.x - t1c.x, f3 * a3.y - t1c.y,
                            f3 * a3.z - t1c.z, f3 * a3.w - t1c.w);
            *(float4*)&t34[1][lr][q * 4] =
                make_float4(f3 * a4.x - t2c.x, f3 * a4.y - t2c.y,
                            f3 * a4.z - t2c.z, f3 * a4.w - t2c.w);
        }
    }
    __syncthreads();
    {
        int lr = t >> 2, n = n0 + lr, cseg = t & 3;
        if (n >= NN) return;
        float txv[T_CHEB * F_IN];
        #pragma unroll
        for (int q = 0; q < 4; ++q) {
            *(float4*)(txv + q * 4)      = *(const float4*)(x  + (size_t)n * F_IN + q * 4);
            *(float4*)(txv + 16 + q * 4) = *(const float4*)(T1 + (size_t)n * F_IN + q * 4);
            *(float4*)(txv + 32 + q * 4) = *(const float4*)(T2 + (size_t)n * F_IN + q * 4);
            *(float4*)(txv + 48 + q * 4) = *(const float4*)&t34[0][lr][q * 4];
            *(float4*)(txv + 64 + q * 4) = *(const float4*)&t34[1][lr][q * 4];
        }
        _Float16* vr = vout + (size_t)n * H + cseg * 24;
        #pragma unroll 4
        for (int c = 0; c < 24; ++c) {
            int o = cseg * 24 + c;
            float s = cheb_b[o];
            #pragma unroll
            for (int kf = 0; kf < T_CHEB * F_IN; ++kf)
                s = fmaf(txv[kf], wlds[kf][o], s);
            vr[c] = (_Float16)s;
        }
    }
}

// ====== per-layer: z-aggregate + 4-way split-K MFMA (16x96, K=576) + LN epilogue ======
// grid 313 x 512 (8 waves). wave: nt-half = wid&1, K-quarter = wid>>1 (9 kc of 16).
// SINGLE DELTA vs R12: B fragments register-prefetched before phase 1 so their
// L2 latency hides under the gather (syncthreads' vmcnt drain guarantees arrival).
__global__ __launch_bounds__(512) void k_layer(
        const _Float16* __restrict__ vcur, const float* __restrict__ hres,
        const int* __restrict__ cnt, const int* __restrict__ ell_r,
        const float4* __restrict__ ell_ea, const _Float16* __restrict__ MfL,
        const float* __restrict__ cb, const float* __restrict__ lg,
        const float* __restrict__ lb, const float* __restrict__ lin_w,
        const float* __restrict__ lin_b,
        float* __restrict__ hnext, _Float16* __restrict__ vnext,
        float* __restrict__ outp, int isLast) {
    __shared__ __align__(16) _Float16 zs[BM2][584];   // 18.7 KB
    __shared__ float hop[4][BM2][100];                // 25.6 KB
    const int n0 = blockIdx.x * BM2;
    const int t = threadIdx.x;

    // ---- phase 0: register-prefetch this wave's B fragments (27 x half4) ----
    const int wid = t >> 6, l = t & 63;
    const int n15 = l & 15, g = l >> 4;
    const int ntBase = (wid & 1) * 3;
    const int kSeg = wid >> 1;            // 0..3
    const int kcBase = kSeg * 9;
    const half4v* Mf4 = (const half4v*)MfL;
    half4v bfr[3][9];
    #pragma unroll
    for (int j = 0; j < 3; ++j) {
        const half4v* Bp = Mf4 + ((size_t)(ntBase + j) * KC_N + kcBase) * 64 + l;
        #pragma unroll
        for (int kk = 0; kk < 9; ++kk) bfr[j][kk] = Bp[kk * 64];
    }

    // ---- phase 1: build z rows (16 lanes/row, first 256 threads) ----
    if (t < 256) {
        int r = t >> 4, lane16 = t & 15;
        int gn = n0 + r, c0 = lane16 * 6;
        float accf[5][6] = {};
        half2v self0 = (half2v)(_Float16)0.f, self1 = self0, self2 = self0;
        if (gn < NN) {
            const _Float16* sv = vcur + (size_t)gn * H + c0;
            self0 = *(const half2v*)(sv + 0);
            self1 = *(const half2v*)(sv + 2);
            self2 = *(const half2v*)(sv + 4);
            int nc = cnt[gn];
            const int* rp = ell_r + gn * MD;
            const float4* eap = ell_ea + gn * MD;
            for (int p = 0; p < nc; ++p) {
                int r2 = rp[p];
                float4 ea = eap[p];
                const _Float16* vv = vcur + (size_t)r2 * H + c0;
                half2v v0 = *(const half2v*)(vv + 0);
                half2v v1 = *(const half2v*)(vv + 2);
                half2v v2 = *(const half2v*)(vv + 4);
                float vf[6] = {(float)v0[0], (float)v0[1], (float)v1[0],
                               (float)v1[1], (float)v2[0], (float)v2[1]};
                const float cf[4] = {ea.x, ea.y, ea.z, ea.w};
                #pragma unroll
                for (int f = 0; f < 4; ++f)
                    #pragma unroll
                    for (int j = 0; j < 6; ++j)
                        accf[f][j] = fmaf(cf[f], vf[j], accf[f][j]);
                #pragma unroll
                for (int j = 0; j < 6; ++j) accf[4][j] += vf[j];
            }
        }
        #pragma unroll
        for (int f = 0; f < 5; ++f) {
            _Float16* zp = &zs[r][f * 96 + c0];
            *(half2v*)(zp + 0) = half2v{(_Float16)accf[f][0], (_Float16)accf[f][1]};
            *(half2v*)(zp + 2) = half2v{(_Float16)accf[f][2], (_Float16)accf[f][3]};
            *(half2v*)(zp + 4) = half2v{(_Float16)accf[f][4], (_Float16)accf[f][5]};
        }
        _Float16* zp = &zs[r][480 + c0];
        *(half2v*)(zp + 0) = self0;
        *(half2v*)(zp + 2) = self1;
        *(half2v*)(zp + 4) = self2;
    }
    __syncthreads();

    // ---- phase 2: MFMA with prefetched B ----
    {
        half4v af[9];
        #pragma unroll
        for (int kk = 0; kk < 9; ++kk)
            af[kk] = *(const half4v*)&zs[n15][(kcBase + kk) * 16 + 4 * g];
        float4v acc3[3] = {};
        #pragma unroll
        for (int j = 0; j < 3; ++j)
            #pragma unroll
            for (int kk = 0; kk < 9; ++kk)
                acc3[j] = MFMA16(af[kk], bfr[j][kk], acc3[j]);
        #pragma unroll
        for (int j = 0; j < 3; ++j) {
            int cc = (ntBase + j) * 16 + n15;
            #pragma unroll
            for (int e = 0; e < 4; ++e)
                hop[kSeg][4 * g + e][cc] = acc3[j][e];
        }
    }
    __syncthreads();

    // ---- phase 3: combine partials + residual + LN + ReLU (or linear head) ----
    if (t < 256) {
        int r = t >> 4, lane16 = t & 15;
        int gn = n0 + r, c0 = lane16 * 6;
        float hv[6];
        #pragma unroll
        for (int j = 0; j < 6; ++j)
            hv[j] = hop[0][r][c0 + j] + hop[1][r][c0 + j]
                  + hop[2][r][c0 + j] + hop[3][r][c0 + j] + cb[c0 + j];
        if (hres && gn < NN) {
            const float* rp = hres + (size_t)gn * H + c0;
            #pragma unroll
            for (int j = 0; j < 6; j += 2) {
                float2 rv = *(const float2*)(rp + j);
                hv[j] += rv.x; hv[j + 1] += rv.y;
            }
        }
        if (!isLast && gn < NN) {
            float* hp = hnext + (size_t)gn * H + c0;
            #pragma unroll
            for (int j = 0; j < 6; j += 2)
                *(float2*)(hp + j) = make_float2(hv[j], hv[j + 1]);
        }
        float s = 0.f;
        #pragma unroll
        for (int j = 0; j < 6; ++j) s += hv[j];
        s += __shfl_xor(s, 1); s += __shfl_xor(s, 2);
        s += __shfl_xor(s, 4); s += __shfl_xor(s, 8);
        float mu = s * (1.0f / H);
        float vvr = 0.f;
        #pragma unroll
        for (int j = 0; j < 6; ++j) { float d = hv[j] - mu; vvr += d * d; }
        vvr += __shfl_xor(vvr, 1); vvr += __shfl_xor(vvr, 2);
        vvr += __shfl_xor(vvr, 4); vvr += __shfl_xor(vvr, 8);
        float is = rsqrtf(vvr * (1.0f / H) + LN_EPSF);
        const float* gp = lg + c0;
        const float* bp = lb + c0;
        float yv[6];
        #pragma unroll
        for (int j = 0; j < 6; ++j)
            yv[j] = fmaxf(fmaf((hv[j] - mu) * is, gp[j], bp[j]), 0.f);
        if (!isLast) {
            if (gn < NN) {
                _Float16* vp = vnext + (size_t)gn * H + c0;
                *(half2v*)(vp + 0) = half2v{(_Float16)yv[0], (_Float16)yv[1]};
                *(half2v*)(vp + 2) = half2v{(_Float16)yv[2], (_Float16)yv[3]};
                *(half2v*)(vp + 4) = half2v{(_Float16)yv[4], (_Float16)yv[5]};
            }
        } else {
            float a0 = 0.f, a1 = 0.f, a2 = 0.f;
            #pragma unroll
            for (int j = 0; j < 6; ++j) {
                int oo = c0 + j;
                a0 = fmaf(yv[j], lin_w[oo * C_OUT + 0], a0);
                a1 = fmaf(yv[j], lin_w[oo * C_OUT + 1], a1);
                a2 = fmaf(yv[j], lin_w[oo * C_OUT + 2], a2);
            }
            a0 += __shfl_xor(a0, 1); a0 += __shfl_xor(a0, 2);
            a0 += __shfl_xor(a0, 4); a0 += __shfl_xor(a0, 8);
            a1 += __shfl_xor(a1, 1); a1 += __shfl_xor(a1, 2);
            a1 += __shfl_xor(a1, 4); a1 += __shfl_xor(a1, 8);
            a2 += __shfl_xor(a2, 1); a2 += __shfl_xor(a2, 2);
            a2 += __shfl_xor(a2, 4); a2 += __shfl_xor(a2, 8);
            if (lane16 == 0 && gn < NN) {
                outp[gn * C_OUT + 0] = a0 + lin_b[0];
                outp[gn * C_OUT + 1] = a1 + lin_b[1];
                outp[gn * C_OUT + 2] = a2 + lin_b[2];
            }
        }
    }
}

extern "C" void kernel_launch(void* const* d_in, const int* in_sizes, int n_in,
                              void* d_out, int out_size, void* d_ws, size_t ws_size,
                              hipStream_t stream) {
    const float* x      = (const float*)d_in[0];
    const int*   row    = (const int*)d_in[1];
    const int*   col    = (const int*)d_in[1] + EE;
    const float* eattr  = (const float*)d_in[2];
    const float* cheb_w = (const float*)d_in[3];
    const float* cheb_b = (const float*)d_in[4];
    const float* enc_w  = (const float*)d_in[5];
    const float* enc_b  = (const float*)d_in[6];
    const float* w1     = (const float*)d_in[7];
    const float* b1     = (const float*)d_in[8];
    const float* w2     = (const float*)d_in[9];
    const float* b2     = (const float*)d_in[10];
    const float* root   = (const float*)d_in[11];
    const float* conv_b = (const float*)d_in[12];
    const float* ln_g   = (const float*)d_in[13];
    const float* ln_b   = (const float*)d_in[14];
    const float* lin_w  = (const float*)d_in[15];
    const float* lin_b  = (const float*)d_in[16];

    char* base = (char*)d_ws;
    size_t off = 0;
    auto alloc = [&](size_t nbytes) {
        char* p = base + off;
        off += (nbytes + 255) / 256 * 256;
        return p;
    };
    float*    deg    = (float*)alloc(NN * 4);
    int*      cnt    = (int*)  alloc(NN * 4);
    size_t    ctl_bytes = off;
    _Float16* Mfrag  = (_Float16*)alloc((size_t)L_LAYERS * FRAG_PER_LAYER * 4 * 2);
    float*    T1     = (float*)alloc((size_t)NN * F_IN * 4);
    float*    T2     = (float*)alloc((size_t)NN * F_IN * 4);
    int*      ell_r  = (int*)  alloc((size_t)NN * MD * 4);
    float*    ell_m  = (float*)alloc((size_t)NN * MD * 4);
    float4*   ell_ea = (float4*)alloc((size_t)NN * MD * 16);
    _Float16* v0     = (_Float16*)alloc((size_t)NN * H * 2);
    _Float16* v1     = (_Float16*)alloc((size_t)NN * H * 2);
    float*    hA     = (float*)alloc((size_t)NN * H * 4);
    float*    hB     = (float*)alloc((size_t)NN * H * 4);
    (void)ws_size; (void)n_in; (void)in_sizes; (void)out_size;

    const int B = 256;
    auto G = [](long n, int b) { return (int)((n + b - 1) / b); };

    (void)hipMemsetAsync(deg, 0, ctl_bytes, stream);
    k_front<<<360, B, 0, stream>>>(enc_w, enc_b, w1, b1, w2, b2, root,
                                   row, col, eattr, Mfrag, deg, cnt, ell_r, ell_m, ell_ea);
    k_chebA<<<G((long)NN * 4, B), B, 0, stream>>>(cnt, ell_r, ell_m, deg, x, T1, T2);
    k_chebB<<<G(NN, 64), B, 0, stream>>>(cnt, ell_r, ell_m, deg, x, T1, T2,
                                         cheb_w, cheb_b, v0);

    _Float16* vbuf[2] = { v0, v1 };
    float*    hbuf[2] = { hA, hB };
    for (int li = 0; li < L_LAYERS; ++li) {
        int isLast = (li == L_LAYERS - 1);
        const _Float16* vcur = vbuf[li & 1];
        _Float16*       vnx  = vbuf[(li + 1) & 1];
        const float*    hres = (li > 0) ? hbuf[(li + 1) & 1] : nullptr;
        float*          hnx  = hbuf[li & 1];
        const float* elg = isLast ? ln_g : ln_g + (li + 1) * H;
        const float* elb = isLast ? ln_b : ln_b + (li + 1) * H;
        k_layer<<<NBT2, 512, 0, stream>>>(
            vcur, hres, cnt, ell_r, ell_ea,
            Mfrag + (size_t)li * FRAG_PER_LAYER * 4,
            conv_b + li * H, elg, elb, lin_w, lin_b,
            hnx, vnx, (float*)d_out, isLast);
    }
}